// Round 2
// baseline (719.705 us; speedup 1.0000x reference)
//
#include <hip/hip_runtime.h>
#include <hip/hip_bf16.h>
#include <math.h>

typedef __bf16 bf16;
typedef bf16 bf16x8 __attribute__((ext_vector_type(8)));
typedef float f32x4 __attribute__((ext_vector_type(4)));

// ---------------------------------------------------------------------------
// Transpose + f32->bf16 cast: src (R x C) f32 row-major -> dst (C x R) bf16,
// dst row stride = dstStride (so multiple sources can pack into one matrix).
// ---------------------------------------------------------------------------
__global__ __launch_bounds__(256) void k_transpose(const float* __restrict__ src,
                                                   bf16* __restrict__ dst,
                                                   int R, int C, int dstStride) {
    __shared__ float tile[32][33];
    int bc = blockIdx.x * 32, br = blockIdx.y * 32;
    int tx = threadIdx.x & 31, ty = threadIdx.x >> 5;  // ty 0..7
    for (int i = 0; i < 4; i++) {
        int r = ty + i * 8;
        tile[r][tx] = src[(size_t)(br + r) * C + bc + tx];
    }
    __syncthreads();
    for (int i = 0; i < 4; i++) {
        int r = ty + i * 8;  // row within dst tile (= src col)
        dst[(size_t)(bc + r) * dstStride + br + tx] = (bf16)tile[tx][r];
    }
}

// ---------------------------------------------------------------------------
// LayerNorm: per-token mean/var over H=2048, write bf16 xn.
// ---------------------------------------------------------------------------
__global__ __launch_bounds__(256) void k_ln(const float* __restrict__ x,
                                            const float* __restrict__ w,
                                            const float* __restrict__ b,
                                            bf16* __restrict__ xn) {
    int s = blockIdx.x;
    int t = threadIdx.x;
    const float* row = x + (size_t)s * 2048;
    const float4* r4 = (const float4*)row;
    float4 A = r4[t * 2], B = r4[t * 2 + 1];
    float sum = A.x + A.y + A.z + A.w + B.x + B.y + B.z + B.w;
    float sq = A.x * A.x + A.y * A.y + A.z * A.z + A.w * A.w +
               B.x * B.x + B.y * B.y + B.z * B.z + B.w * B.w;
    for (int off = 32; off; off >>= 1) {
        sum += __shfl_down(sum, off);
        sq  += __shfl_down(sq, off);
    }
    __shared__ float rs[4], rq[4];
    if ((t & 63) == 0) { rs[t >> 6] = sum; rq[t >> 6] = sq; }
    __syncthreads();
    float S = rs[0] + rs[1] + rs[2] + rs[3];
    float Q = rq[0] + rq[1] + rq[2] + rq[3];
    float mu = S * (1.0f / 2048.0f);
    float var = Q * (1.0f / 2048.0f) - mu * mu;
    float rstd = rsqrtf(var + 1e-5f);
    float vals[8] = {A.x, A.y, A.z, A.w, B.x, B.y, B.z, B.w};
    bf16x8 ov;
    int j0 = t * 8;
    for (int i = 0; i < 8; i++)
        ov[i] = (bf16)((vals[i] - mu) * rstd * w[j0 + i] + b[j0 + i]);
    *(bf16x8*)&xn[(size_t)s * 2048 + j0] = ov;
}

// ---------------------------------------------------------------------------
// MFMA bf16 GEMM: C(MxN) = A(MxK) @ Bt(NxK)^T.  128x128 tile, BK=64,
// 4 waves (2x2), each wave 64x64 via 4x4 frags of 16x16x32.
// MODE 0: Cf = acc                  (qkv)
// MODE 1: Cb = gelu_tanh(acc+bias)  (mlp up, bf16 out)
// MODE 2: Cf = add + acc            (wo + residual)
// MODE 3: Cf += acc + bias          (mlp down accumulate)
// ---------------------------------------------------------------------------
template <int MODE>
__global__ __launch_bounds__(256) void k_gemm(const bf16* __restrict__ A,
                                              const bf16* __restrict__ Bt,
                                              int M, int N, int K,
                                              float* __restrict__ Cf,
                                              bf16* __restrict__ Cb,
                                              const float* __restrict__ bias,
                                              const float* __restrict__ add) {
    __shared__ bf16 As[128][72];  // +8 pad: row stride 144B (16B aligned)
    __shared__ bf16 Bs[128][72];
    int t = threadIdx.x;
    int bm = blockIdx.y, bn = blockIdx.x;
    int wid = t >> 6, l = t & 63, lr = l & 15, lg = l >> 4;
    int wm = wid >> 1, wn = wid & 1;
    f32x4 acc[4][4] = {};
    int ar = t >> 3, ac = (t & 7) * 8;
    const bf16* Ab = A + (size_t)(bm * 128) * K;
    const bf16* Bb = Bt + (size_t)(bn * 128) * K;
    int nkt = K >> 6;
    for (int kt = 0; kt < nkt; ++kt) {
        int k0 = kt * 64;
        bf16x8 av[4], bv[4];
        for (int i = 0; i < 4; i++) {
            av[i] = *(const bf16x8*)&Ab[(size_t)(i * 32 + ar) * K + k0 + ac];
            bv[i] = *(const bf16x8*)&Bb[(size_t)(i * 32 + ar) * K + k0 + ac];
        }
        __syncthreads();  // previous iter's LDS reads complete
        for (int i = 0; i < 4; i++) {
            *(bf16x8*)&As[i * 32 + ar][ac] = av[i];
            *(bf16x8*)&Bs[i * 32 + ar][ac] = bv[i];
        }
        __syncthreads();
        for (int kk = 0; kk < 2; kk++) {
            bf16x8 a[4], b[4];
            for (int fm = 0; fm < 4; fm++)
                a[fm] = *(const bf16x8*)&As[wm * 64 + fm * 16 + lr][kk * 32 + lg * 8];
            for (int fn = 0; fn < 4; fn++)
                b[fn] = *(const bf16x8*)&Bs[wn * 64 + fn * 16 + lr][kk * 32 + lg * 8];
            for (int fm = 0; fm < 4; fm++)
                for (int fn = 0; fn < 4; fn++)
                    acc[fm][fn] = __builtin_amdgcn_mfma_f32_16x16x32_bf16(
                        a[fm], b[fn], acc[fm][fn], 0, 0, 0);
        }
    }
    for (int fm = 0; fm < 4; fm++)
        for (int fn = 0; fn < 4; fn++) {
            int col = bn * 128 + wn * 64 + fn * 16 + lr;
            for (int r = 0; r < 4; r++) {
                int row = bm * 128 + wm * 64 + fm * 16 + lg * 4 + r;
                size_t idx = (size_t)row * N + col;
                float v = acc[fm][fn][r];
                if constexpr (MODE == 0) {
                    Cf[idx] = v;
                } else if constexpr (MODE == 1) {
                    v += bias[col];
                    float g = 0.5f * v * (1.0f + tanhf(0.7978845608028654f *
                                                       (v + 0.044715f * v * v * v)));
                    Cb[idx] = (bf16)g;
                } else if constexpr (MODE == 2) {
                    Cf[idx] = add[idx] + v;
                } else {
                    Cf[idx] += v + bias[col];
                }
            }
        }
}

// ---------------------------------------------------------------------------
// tau: tok = gelu_exact(qkv row); tau_q[s,h] = tanh(tok . tau_wq[:,h]) + taupos
// one block per token; 64 dot products of length 3072 split over 4 chunks.
// NOTE: position_ids arrives as int32 (harness converts integer inputs).
// ---------------------------------------------------------------------------
__global__ __launch_bounds__(256) void k_tau(const float* __restrict__ qkv,
                                             const float* __restrict__ twq,
                                             const float* __restrict__ twv,
                                             const float* __restrict__ alpha,
                                             const int* __restrict__ pos,
                                             float* __restrict__ tauq,
                                             float* __restrict__ tauv) {
    int s = blockIdx.x;
    __shared__ float tok[3072];
    __shared__ float part[4][64];
    const float* row = qkv + (size_t)s * 3072;
    for (int j = threadIdx.x; j < 3072; j += 256) {
        float x = row[j];
        tok[j] = x * 0.5f * (1.0f + erff(x * 0.7071067811865475f));
    }
    __syncthreads();
    int h = threadIdx.x & 63;       // 0..31 -> tau_q, 32..63 -> tau_v
    int chunk = threadIdx.x >> 6;   // 0..3
    const float* W = (h < 32) ? twq : twv;
    int hh = h & 31;
    float acc = 0.0f;
    int j0 = chunk * 768;
    for (int j = j0; j < j0 + 768; ++j) acc += tok[j] * W[j * 32 + hh];
    part[chunk][h] = acc;
    __syncthreads();
    if (chunk == 0) {
        float tot = part[0][h] + part[1][h] + part[2][h] + part[3][h];
        float pf = (float)(pos[s] + 1);
        float lp = logf(pf);
        float tp = 1.0f + (1.0f / (1.0f + expf(-alpha[hh] * lp)) - 0.5f);
        float val = tanhf(tot) + tp;
        if (h < 32) tauq[s * 32 + hh] = val;
        else        tauv[s * 32 + hh] = val;
    }
}

// ---------------------------------------------------------------------------
// Head build: q*tau_q*0.125 -> rope -> Qr(s,2048); k -> rope -> Kr(s,512);
// v*tau_v -> Vt (kvh, d, s) transposed for PV fragments.
// RoPE: out[2j] = r[j]c - i[j]s, out[2j+1] = r[j]s + i[j]c; r=x[0:16], i=x[16:32].
// One wave per token (4 tokens per block).
// ---------------------------------------------------------------------------
__global__ __launch_bounds__(256) void k_heads(const float* __restrict__ qkv,
                                               const float* __restrict__ cosb,
                                               const float* __restrict__ sinb,
                                               const float* __restrict__ tauq,
                                               const float* __restrict__ tauv,
                                               bf16* __restrict__ Qr,
                                               bf16* __restrict__ Kr,
                                               bf16* __restrict__ Vt) {
    int s = blockIdx.x * 4 + (threadIdx.x >> 6);
    int d = threadIdx.x & 63;
    int j = (d >> 1) & 15;
    float c = cosb[s * 16 + j], sn = sinb[s * 16 + j];
    const float* row = qkv + (size_t)s * 3072;
    for (int h = 0; h < 32; ++h) {
        float x = row[h * 64 + d] * tauq[s * 32 + h] * 0.125f;
        float xr = __shfl(x, j);
        float xi = __shfl(x, j + 16);
        float out = (d < 32) ? ((d & 1) ? (xr * sn + xi * c) : (xr * c - xi * sn)) : x;
        Qr[(size_t)s * 2048 + h * 64 + d] = (bf16)out;
    }
    for (int h = 0; h < 8; ++h) {
        float x = row[2048 + h * 64 + d];
        float xr = __shfl(x, j);
        float xi = __shfl(x, j + 16);
        float out = (d < 32) ? ((d & 1) ? (xr * sn + xi * c) : (xr * c - xi * sn)) : x;
        Kr[(size_t)s * 512 + h * 64 + d] = (bf16)out;
    }
    for (int h = 0; h < 8; ++h) {
        float x = row[2560 + h * 64 + d] * tauv[s * 32 + h];
        Vt[((size_t)h * 64 + d) * 2048 + s] = (bf16)x;
    }
}

// ---------------------------------------------------------------------------
// Flash attention (causal, GQA 32/8, D=64). One wave per 16-row q-tile,
// 32-key k-tiles. QK^T: 4 mfma; PV: 4 mfma (P via wave-private LDS).
// 1/8 scale pre-folded into Q.
// ---------------------------------------------------------------------------
__global__ __launch_bounds__(256) void k_attn(const bf16* __restrict__ Q,
                                              const bf16* __restrict__ K,
                                              const bf16* __restrict__ Vt,
                                              bf16* __restrict__ O) {
    __shared__ bf16 plds[4][16][40];  // pad 32->40 (80B row stride)
    int w = threadIdx.x >> 6, l = threadIdx.x & 63, lr = l & 15, lg = l >> 4;
    int h = blockIdx.y, qt = blockIdx.x * 4 + w, kvh = h >> 2;
    int qrow0 = qt * 16;
    bf16x8 q0 = *(const bf16x8*)&Q[(size_t)(qrow0 + lr) * 2048 + h * 64 + lg * 8];
    bf16x8 q1 = *(const bf16x8*)&Q[(size_t)(qrow0 + lr) * 2048 + h * 64 + 32 + lg * 8];
    f32x4 o[4] = {};
    float m[4] = {-3e38f, -3e38f, -3e38f, -3e38f};
    float ll[4] = {};
    int nkt = (qrow0 + 15) / 32 + 1;
    for (int kt = 0; kt < nkt; ++kt) {
        int kb = kt * 32;
        f32x4 sc[2];
        for (int kc = 0; kc < 2; kc++) {
            const bf16* kp = &K[(size_t)(kb + kc * 16 + lr) * 512 + kvh * 64];
            bf16x8 b0 = *(const bf16x8*)&kp[lg * 8];
            bf16x8 b1 = *(const bf16x8*)&kp[32 + lg * 8];
            f32x4 z = {};
            z = __builtin_amdgcn_mfma_f32_16x16x32_bf16(q0, b0, z, 0, 0, 0);
            sc[kc] = __builtin_amdgcn_mfma_f32_16x16x32_bf16(q1, b1, z, 0, 0, 0);
        }
        float p[2][4], al[4];
        for (int r = 0; r < 4; r++) {
            int qr = qrow0 + lg * 4 + r;
            for (int kc = 0; kc < 2; kc++) {
                int kcol = kb + kc * 16 + lr;
                if (kcol > qr) sc[kc][r] = -1e30f;
            }
            float t2 = fmaxf(sc[0][r], sc[1][r]);
            for (int off = 1; off < 16; off <<= 1) t2 = fmaxf(t2, __shfl_xor(t2, off));
            float mn = fmaxf(m[r], t2);
            al[r] = __expf(m[r] - mn);
            m[r] = mn;
            p[0][r] = __expf(sc[0][r] - mn);
            p[1][r] = __expf(sc[1][r] - mn);
            float rsum = p[0][r] + p[1][r];
            for (int off = 1; off < 16; off <<= 1) rsum += __shfl_xor(rsum, off);
            ll[r] = ll[r] * al[r] + rsum;
        }
        for (int fn = 0; fn < 4; fn++)
            for (int r = 0; r < 4; r++) o[fn][r] *= al[r];
        for (int kc = 0; kc < 2; kc++)
            for (int r = 0; r < 4; r++)
                plds[w][lg * 4 + r][kc * 16 + lr] = (bf16)p[kc][r];
        asm volatile("s_waitcnt lgkmcnt(0)" ::: "memory");
        bf16x8 pa = *(const bf16x8*)&plds[w][lr][lg * 8];
        for (int fn = 0; fn < 4; fn++) {
            bf16x8 bv = *(const bf16x8*)&Vt[(size_t)(kvh * 64 + fn * 16 + lr) * 2048 + kb + lg * 8];
            o[fn] = __builtin_amdgcn_mfma_f32_16x16x32_bf16(pa, bv, o[fn], 0, 0, 0);
        }
    }
    for (int fn = 0; fn < 4; fn++)
        for (int r = 0; r < 4; r++)
            O[(size_t)(qrow0 + lg * 4 + r) * 2048 + h * 64 + fn * 16 + lr] =
                (bf16)(o[fn][r] / ll[r]);
}

// ---------------------------------------------------------------------------
extern "C" void kernel_launch(void* const* d_in, const int* in_sizes, int n_in,
                              void* d_out, int out_size, void* d_ws, size_t ws_size,
                              hipStream_t stream) {
    const float* hidden = (const float*)d_in[0];
    const int*   pos    = (const int*)d_in[1];   // harness converts int64 -> int32
    const float* cosb   = (const float*)d_in[2];
    const float* sinb   = (const float*)d_in[3];
    const float* ln_w   = (const float*)d_in[4];
    const float* ln_b   = (const float*)d_in[5];
    const float* wq     = (const float*)d_in[6];
    const float* wk     = (const float*)d_in[7];
    const float* wv     = (const float*)d_in[8];
    const float* wo     = (const float*)d_in[9];
    const float* twq    = (const float*)d_in[10];
    const float* twv    = (const float*)d_in[11];
    const float* alpha  = (const float*)d_in[12];
    const float* up_w   = (const float*)d_in[13];
    const float* up_b   = (const float*)d_in[14];
    const float* down_w = (const float*)d_in[15];
    const float* down_b = (const float*)d_in[16];
    float* out = (float*)d_out;

    char* p = (char*)d_ws;
    auto alloc = [&](size_t n) -> char* {
        char* r = p;
        p += (n + 255) & ~(size_t)255;
        return r;
    };
    bf16* wqkvT = (bf16*)alloc((size_t)3072 * 2048 * 2);
    bf16* woT   = (bf16*)alloc((size_t)2048 * 2048 * 2);
    bf16* upT   = (bf16*)alloc((size_t)8192 * 2048 * 2);
    bf16* downT = (bf16*)alloc((size_t)2048 * 8192 * 2);
    bf16* xn    = (bf16*)alloc((size_t)2048 * 2048 * 2);
    float* qkv  = (float*)alloc((size_t)2048 * 3072 * 4);
    float* tauq = (float*)alloc((size_t)2048 * 32 * 4);
    float* tauv = (float*)alloc((size_t)2048 * 32 * 4);
    bf16* Qr    = (bf16*)alloc((size_t)2048 * 2048 * 2);
    bf16* Kr    = (bf16*)alloc((size_t)2048 * 512 * 2);
    bf16* Vt    = (bf16*)alloc((size_t)8 * 64 * 2048 * 2);
    bf16* aout  = (bf16*)alloc((size_t)2048 * 2048 * 2);
    bf16* hbuf  = (bf16*)alloc((size_t)2048 * 8192 * 2);

    // weights -> bf16, transposed to (N, K)
    k_transpose<<<dim3(64, 64), 256, 0, stream>>>(wq, wqkvT, 2048, 2048, 2048);
    k_transpose<<<dim3(16, 64), 256, 0, stream>>>(wk, wqkvT + (size_t)2048 * 2048, 2048, 512, 2048);
    k_transpose<<<dim3(16, 64), 256, 0, stream>>>(wv, wqkvT + (size_t)2560 * 2048, 2048, 512, 2048);
    k_transpose<<<dim3(64, 64), 256, 0, stream>>>(wo, woT, 2048, 2048, 2048);
    k_transpose<<<dim3(256, 64), 256, 0, stream>>>(up_w, upT, 2048, 8192, 2048);
    k_transpose<<<dim3(64, 256), 256, 0, stream>>>(down_w, downT, 8192, 2048, 8192);

    k_ln<<<2048, 256, 0, stream>>>(hidden, ln_w, ln_b, xn);

    // qkv = xn @ [wq|wk|wv]
    k_gemm<0><<<dim3(24, 16), 256, 0, stream>>>(xn, wqkvT, 2048, 3072, 2048,
                                                qkv, nullptr, nullptr, nullptr);

    k_tau<<<2048, 256, 0, stream>>>(qkv, twq, twv, alpha, pos, tauq, tauv);
    k_heads<<<512, 256, 0, stream>>>(qkv, cosb, sinb, tauq, tauv, Qr, Kr, Vt);

    k_attn<<<dim3(32, 32), 256, 0, stream>>>(Qr, Kr, Vt, aout);

    // out = hidden + attn @ wo
    k_gemm<2><<<dim3(16, 16), 256, 0, stream>>>(aout, woT, 2048, 2048, 2048,
                                                out, nullptr, nullptr, hidden);
    // h = gelu_tanh(xn @ up_w + up_b)
    k_gemm<1><<<dim3(64, 16), 256, 0, stream>>>(xn, upT, 2048, 8192, 2048,
                                                nullptr, hbuf, up_b, nullptr);
    // out += h @ down_w + down_b
    k_gemm<3><<<dim3(16, 16), 256, 0, stream>>>(hbuf, downT, 2048, 2048, 8192,
                                                out, nullptr, down_b, nullptr);
}

// Round 3
// 611.149 us; speedup vs baseline: 1.1776x; 1.1776x over previous
//
#include <hip/hip_runtime.h>
#include <hip/hip_bf16.h>
#include <math.h>

typedef __bf16 bf16;
typedef bf16 bf16x4 __attribute__((ext_vector_type(4)));
typedef bf16 bf16x8 __attribute__((ext_vector_type(8)));
typedef float f32x4 __attribute__((ext_vector_type(4)));

// ---------------------------------------------------------------------------
// Transpose + f32->bf16 cast: src (R x C) f32 row-major -> dst (C x R) bf16.
// ---------------------------------------------------------------------------
__global__ __launch_bounds__(256) void k_transpose(const float* __restrict__ src,
                                                   bf16* __restrict__ dst,
                                                   int R, int C, int dstStride) {
    __shared__ float tile[32][33];
    int bc = blockIdx.x * 32, br = blockIdx.y * 32;
    int tx = threadIdx.x & 31, ty = threadIdx.x >> 5;  // ty 0..7
    for (int i = 0; i < 4; i++) {
        int r = ty + i * 8;
        tile[r][tx] = src[(size_t)(br + r) * C + bc + tx];
    }
    __syncthreads();
    for (int i = 0; i < 4; i++) {
        int r = ty + i * 8;
        dst[(size_t)(bc + r) * dstStride + br + tx] = (bf16)tile[tx][r];
    }
}

// ---------------------------------------------------------------------------
// LayerNorm: per-token mean/var over H=2048, write bf16 xn.
// ---------------------------------------------------------------------------
__global__ __launch_bounds__(256) void k_ln(const float* __restrict__ x,
                                            const float* __restrict__ w,
                                            const float* __restrict__ b,
                                            bf16* __restrict__ xn) {
    int s = blockIdx.x;
    int t = threadIdx.x;
    const float* row = x + (size_t)s * 2048;
    const float4* r4 = (const float4*)row;
    float4 A = r4[t * 2], B = r4[t * 2 + 1];
    float sum = A.x + A.y + A.z + A.w + B.x + B.y + B.z + B.w;
    float sq = A.x * A.x + A.y * A.y + A.z * A.z + A.w * A.w +
               B.x * B.x + B.y * B.y + B.z * B.z + B.w * B.w;
    for (int off = 32; off; off >>= 1) {
        sum += __shfl_down(sum, off);
        sq  += __shfl_down(sq, off);
    }
    __shared__ float rs[4], rq[4];
    if ((t & 63) == 0) { rs[t >> 6] = sum; rq[t >> 6] = sq; }
    __syncthreads();
    float S = rs[0] + rs[1] + rs[2] + rs[3];
    float Q = rq[0] + rq[1] + rq[2] + rq[3];
    float mu = S * (1.0f / 2048.0f);
    float var = Q * (1.0f / 2048.0f) - mu * mu;
    float rstd = rsqrtf(var + 1e-5f);
    float vals[8] = {A.x, A.y, A.z, A.w, B.x, B.y, B.z, B.w};
    bf16x8 ov;
    int j0 = t * 8;
    for (int i = 0; i < 8; i++)
        ov[i] = (bf16)((vals[i] - mu) * rstd * w[j0 + i] + b[j0 + i]);
    *(bf16x8*)&xn[(size_t)s * 2048 + j0] = ov;
}

// ---------------------------------------------------------------------------
// MFMA bf16 GEMM: C(MxN) = A(MxK) @ Bt(NxK)^T.  128x128 tile, BK=64.
// ---------------------------------------------------------------------------
template <int MODE>
__global__ __launch_bounds__(256) void k_gemm(const bf16* __restrict__ A,
                                              const bf16* __restrict__ Bt,
                                              int M, int N, int K,
                                              float* __restrict__ Cf,
                                              bf16* __restrict__ Cb,
                                              const float* __restrict__ bias,
                                              const float* __restrict__ add) {
    __shared__ bf16 As[128][72];
    __shared__ bf16 Bs[128][72];
    int t = threadIdx.x;
    int bm = blockIdx.y, bn = blockIdx.x;
    int wid = t >> 6, l = t & 63, lr = l & 15, lg = l >> 4;
    int wm = wid >> 1, wn = wid & 1;
    f32x4 acc[4][4] = {};
    int ar = t >> 3, ac = (t & 7) * 8;
    const bf16* Ab = A + (size_t)(bm * 128) * K;
    const bf16* Bb = Bt + (size_t)(bn * 128) * K;
    int nkt = K >> 6;
    for (int kt = 0; kt < nkt; ++kt) {
        int k0 = kt * 64;
        bf16x8 av[4], bv[4];
        for (int i = 0; i < 4; i++) {
            av[i] = *(const bf16x8*)&Ab[(size_t)(i * 32 + ar) * K + k0 + ac];
            bv[i] = *(const bf16x8*)&Bb[(size_t)(i * 32 + ar) * K + k0 + ac];
        }
        __syncthreads();
        for (int i = 0; i < 4; i++) {
            *(bf16x8*)&As[i * 32 + ar][ac] = av[i];
            *(bf16x8*)&Bs[i * 32 + ar][ac] = bv[i];
        }
        __syncthreads();
        for (int kk = 0; kk < 2; kk++) {
            bf16x8 a[4], b[4];
            for (int fm = 0; fm < 4; fm++)
                a[fm] = *(const bf16x8*)&As[wm * 64 + fm * 16 + lr][kk * 32 + lg * 8];
            for (int fn = 0; fn < 4; fn++)
                b[fn] = *(const bf16x8*)&Bs[wn * 64 + fn * 16 + lr][kk * 32 + lg * 8];
            for (int fm = 0; fm < 4; fm++)
                for (int fn = 0; fn < 4; fn++)
                    acc[fm][fn] = __builtin_amdgcn_mfma_f32_16x16x32_bf16(
                        a[fm], b[fn], acc[fm][fn], 0, 0, 0);
        }
    }
    for (int fm = 0; fm < 4; fm++)
        for (int fn = 0; fn < 4; fn++) {
            int col = bn * 128 + wn * 64 + fn * 16 + lr;
            for (int r = 0; r < 4; r++) {
                int row = bm * 128 + wm * 64 + fm * 16 + lg * 4 + r;
                size_t idx = (size_t)row * N + col;
                float v = acc[fm][fn][r];
                if constexpr (MODE == 0) {
                    Cf[idx] = v;
                } else if constexpr (MODE == 1) {
                    v += bias[col];
                    float g = 0.5f * v * (1.0f + tanhf(0.7978845608028654f *
                                                       (v + 0.044715f * v * v * v)));
                    Cb[idx] = (bf16)g;
                } else if constexpr (MODE == 2) {
                    Cf[idx] = add[idx] + v;
                } else {
                    Cf[idx] += v + bias[col];
                }
            }
        }
}

// ---------------------------------------------------------------------------
// tau weights per token (position_ids arrive as int32 from the harness).
// ---------------------------------------------------------------------------
__global__ __launch_bounds__(256) void k_tau(const float* __restrict__ qkv,
                                             const float* __restrict__ twq,
                                             const float* __restrict__ twv,
                                             const float* __restrict__ alpha,
                                             const int* __restrict__ pos,
                                             float* __restrict__ tauq,
                                             float* __restrict__ tauv) {
    int s = blockIdx.x;
    __shared__ float tok[3072];
    __shared__ float part[4][64];
    const float* row = qkv + (size_t)s * 3072;
    for (int j = threadIdx.x; j < 3072; j += 256) {
        float x = row[j];
        tok[j] = x * 0.5f * (1.0f + erff(x * 0.7071067811865475f));
    }
    __syncthreads();
    int h = threadIdx.x & 63;
    int chunk = threadIdx.x >> 6;
    const float* W = (h < 32) ? twq : twv;
    int hh = h & 31;
    float acc = 0.0f;
    int j0 = chunk * 768;
    for (int j = j0; j < j0 + 768; ++j) acc += tok[j] * W[j * 32 + hh];
    part[chunk][h] = acc;
    __syncthreads();
    if (chunk == 0) {
        float tot = part[0][h] + part[1][h] + part[2][h] + part[3][h];
        float pf = (float)(pos[s] + 1);
        float lp = logf(pf);
        float tp = 1.0f + (1.0f / (1.0f + expf(-alpha[hh] * lp)) - 0.5f);
        float val = tanhf(tot) + tp;
        if (h < 32) tauq[s * 32 + hh] = val;
        else        tauv[s * 32 + hh] = val;
    }
}

// ---------------------------------------------------------------------------
// Head build: RoPE + tau scaling; Vt stored (kvh*64+d, s).
// ---------------------------------------------------------------------------
__global__ __launch_bounds__(256) void k_heads(const float* __restrict__ qkv,
                                               const float* __restrict__ cosb,
                                               const float* __restrict__ sinb,
                                               const float* __restrict__ tauq,
                                               const float* __restrict__ tauv,
                                               bf16* __restrict__ Qr,
                                               bf16* __restrict__ Kr,
                                               bf16* __restrict__ Vt) {
    int s = blockIdx.x * 4 + (threadIdx.x >> 6);
    int d = threadIdx.x & 63;
    int j = (d >> 1) & 15;
    float c = cosb[s * 16 + j], sn = sinb[s * 16 + j];
    const float* row = qkv + (size_t)s * 3072;
    for (int h = 0; h < 32; ++h) {
        float x = row[h * 64 + d] * tauq[s * 32 + h] * 0.125f;
        float xr = __shfl(x, j);
        float xi = __shfl(x, j + 16);
        float out = (d < 32) ? ((d & 1) ? (xr * sn + xi * c) : (xr * c - xi * sn)) : x;
        Qr[(size_t)s * 2048 + h * 64 + d] = (bf16)out;
    }
    for (int h = 0; h < 8; ++h) {
        float x = row[2048 + h * 64 + d];
        float xr = __shfl(x, j);
        float xi = __shfl(x, j + 16);
        float out = (d < 32) ? ((d & 1) ? (xr * sn + xi * c) : (xr * c - xi * sn)) : x;
        Kr[(size_t)s * 512 + h * 64 + d] = (bf16)out;
    }
    for (int h = 0; h < 8; ++h) {
        float x = row[2560 + h * 64 + d] * tauv[s * 32 + h];
        Vt[((size_t)h * 64 + d) * 2048 + s] = (bf16)x;
    }
}

// ---------------------------------------------------------------------------
// Flash attention v2 (causal, GQA 32/8, D=64).
// Swapped-operand layout: scores/O live with q = lane&15 -> softmax state is
// lane-scalar (2 shfl_xor total per tile). Each wave serially handles q-tiles
// {slot, 127-slot} for uniform causal work. K prefetched 1 tile ahead; V
// issued at tile start. Grid (32 heads, 16), 4 waves/block.
// ---------------------------------------------------------------------------
__global__ __launch_bounds__(256) void k_attn(const bf16* __restrict__ Q,
                                              const bf16* __restrict__ K,
                                              const bf16* __restrict__ Vt,
                                              bf16* __restrict__ O) {
    __shared__ bf16 plds[4][16][40];
    int w = threadIdx.x >> 6, l = threadIdx.x & 63, lr = l & 15, lg = l >> 4;
    int h = blockIdx.x, kvh = h >> 2;
    int slot = blockIdx.y * 4 + w;
    const bf16* Kb = K + (size_t)kvh * 64;
    const bf16* Vb = Vt + ((size_t)kvh * 64) * 2048;

    for (int pass = 0; pass < 2; ++pass) {
        int qt = pass ? (127 - slot) : slot;
        int qrow0 = qt * 16;
        int qg = qrow0 + lr;
        bf16x8 q0 = *(const bf16x8*)&Q[(size_t)qg * 2048 + h * 64 + lg * 8];
        bf16x8 q1 = *(const bf16x8*)&Q[(size_t)qg * 2048 + h * 64 + 32 + lg * 8];
        f32x4 o[4] = {};
        float m = -3e38f, ll = 0.0f;
        int nkt = (qrow0 + 15) / 32 + 1;
        // K prologue (tile 0): frag [kc][d0]
        bf16x8 kf[4];
        for (int kc = 0; kc < 2; kc++)
            for (int dd = 0; dd < 2; dd++)
                kf[kc * 2 + dd] = *(const bf16x8*)&Kb[(size_t)(kc * 16 + lr) * 512 + dd * 32 + lg * 8];
        for (int kt = 0; kt < nkt; ++kt) {
            int kb = kt * 32;
            // V loads for current tile (consumed after softmax)
            bf16x8 vf[4];
            for (int fn = 0; fn < 4; fn++)
                vf[fn] = *(const bf16x8*)&Vb[(size_t)(fn * 16 + lr) * 2048 + kb + lg * 8];
            // QK^T (swapped): sc[kc] lane holds S[q=lr][k = kb+kc*16+lg*4+r]
            f32x4 sc[2];
            for (int kc = 0; kc < 2; kc++) {
                f32x4 z = {};
                z = __builtin_amdgcn_mfma_f32_16x16x32_bf16(kf[kc * 2], q0, z, 0, 0, 0);
                sc[kc] = __builtin_amdgcn_mfma_f32_16x16x32_bf16(kf[kc * 2 + 1], q1, z, 0, 0, 0);
            }
            // prefetch K for next tile
            int kbn = (kt + 1 < nkt) ? (kt + 1) * 32 : kt * 32;
            for (int kc = 0; kc < 2; kc++)
                for (int dd = 0; dd < 2; dd++)
                    kf[kc * 2 + dd] = *(const bf16x8*)&Kb[(size_t)(kbn + kc * 16 + lr) * 512 + dd * 32 + lg * 8];
            // causal mask + online softmax (lane-scalar state, q = lr)
            float tmax = -3e38f;
            for (int kc = 0; kc < 2; kc++)
                for (int r = 0; r < 4; r++) {
                    int kg = kb + kc * 16 + lg * 4 + r;
                    if (kg > qg) sc[kc][r] = -1e30f;
                    tmax = fmaxf(tmax, sc[kc][r]);
                }
            tmax = fmaxf(tmax, __shfl_xor(tmax, 16));
            tmax = fmaxf(tmax, __shfl_xor(tmax, 32));
            float mn = fmaxf(m, tmax);
            float al = __expf(m - mn);
            m = mn;
            float rsum = 0.0f;
            f32x4 p[2];
            for (int kc = 0; kc < 2; kc++)
                for (int r = 0; r < 4; r++) {
                    float pv = __expf(sc[kc][r] - mn);
                    p[kc][r] = pv;
                    rsum += pv;
                }
            rsum += __shfl_xor(rsum, 16);
            rsum += __shfl_xor(rsum, 32);
            ll = ll * al + rsum;
            for (int fn = 0; fn < 4; fn++)
                for (int r = 0; r < 4; r++) o[fn][r] *= al;
            // P -> LDS [q][k] as two 8B writes, read back as A-frag rows q=lr
            for (int kc = 0; kc < 2; kc++) {
                bf16x4 pk;
                for (int r = 0; r < 4; r++) pk[r] = (bf16)p[kc][r];
                *(bf16x4*)&plds[w][lr][kc * 16 + lg * 4] = pk;
            }
            asm volatile("s_waitcnt lgkmcnt(0)" ::: "memory");
            bf16x8 pa = *(const bf16x8*)&plds[w][lr][lg * 8];
            // PV (swapped): o[fn][r] = O[q=lr][d = fn*16 + lg*4 + r]
            for (int fn = 0; fn < 4; fn++)
                o[fn] = __builtin_amdgcn_mfma_f32_16x16x32_bf16(vf[fn], pa, o[fn], 0, 0, 0);
        }
        float rinv = 1.0f / ll;
        for (int fn = 0; fn < 4; fn++) {
            bf16x4 ov;
            for (int r = 0; r < 4; r++) ov[r] = (bf16)(o[fn][r] * rinv);
            *(bf16x4*)&O[(size_t)qg * 2048 + h * 64 + fn * 16 + lg * 4] = ov;
        }
    }
}

// ---------------------------------------------------------------------------
extern "C" void kernel_launch(void* const* d_in, const int* in_sizes, int n_in,
                              void* d_out, int out_size, void* d_ws, size_t ws_size,
                              hipStream_t stream) {
    const float* hidden = (const float*)d_in[0];
    const int*   pos    = (const int*)d_in[1];   // harness converts int64 -> int32
    const float* cosb   = (const float*)d_in[2];
    const float* sinb   = (const float*)d_in[3];
    const float* ln_w   = (const float*)d_in[4];
    const float* ln_b   = (const float*)d_in[5];
    const float* wq     = (const float*)d_in[6];
    const float* wk     = (const float*)d_in[7];
    const float* wv     = (const float*)d_in[8];
    const float* wo     = (const float*)d_in[9];
    const float* twq    = (const float*)d_in[10];
    const float* twv    = (const float*)d_in[11];
    const float* alpha  = (const float*)d_in[12];
    const float* up_w   = (const float*)d_in[13];
    const float* up_b   = (const float*)d_in[14];
    const float* down_w = (const float*)d_in[15];
    const float* down_b = (const float*)d_in[16];
    float* out = (float*)d_out;

    char* p = (char*)d_ws;
    auto alloc = [&](size_t n) -> char* {
        char* r = p;
        p += (n + 255) & ~(size_t)255;
        return r;
    };
    bf16* wqkvT = (bf16*)alloc((size_t)3072 * 2048 * 2);
    bf16* woT   = (bf16*)alloc((size_t)2048 * 2048 * 2);
    bf16* upT   = (bf16*)alloc((size_t)8192 * 2048 * 2);
    bf16* downT = (bf16*)alloc((size_t)2048 * 8192 * 2);
    bf16* xn    = (bf16*)alloc((size_t)2048 * 2048 * 2);
    float* qkv  = (float*)alloc((size_t)2048 * 3072 * 4);
    float* tauq = (float*)alloc((size_t)2048 * 32 * 4);
    float* tauv = (float*)alloc((size_t)2048 * 32 * 4);
    bf16* Qr    = (bf16*)alloc((size_t)2048 * 2048 * 2);
    bf16* Kr    = (bf16*)alloc((size_t)2048 * 512 * 2);
    bf16* Vt    = (bf16*)alloc((size_t)8 * 64 * 2048 * 2);
    bf16* aout  = (bf16*)alloc((size_t)2048 * 2048 * 2);
    bf16* hbuf  = (bf16*)alloc((size_t)2048 * 8192 * 2);

    k_transpose<<<dim3(64, 64), 256, 0, stream>>>(wq, wqkvT, 2048, 2048, 2048);
    k_transpose<<<dim3(16, 64), 256, 0, stream>>>(wk, wqkvT + (size_t)2048 * 2048, 2048, 512, 2048);
    k_transpose<<<dim3(16, 64), 256, 0, stream>>>(wv, wqkvT + (size_t)2560 * 2048, 2048, 512, 2048);
    k_transpose<<<dim3(64, 64), 256, 0, stream>>>(wo, woT, 2048, 2048, 2048);
    k_transpose<<<dim3(256, 64), 256, 0, stream>>>(up_w, upT, 2048, 8192, 2048);
    k_transpose<<<dim3(64, 256), 256, 0, stream>>>(down_w, downT, 8192, 2048, 8192);

    k_ln<<<2048, 256, 0, stream>>>(hidden, ln_w, ln_b, xn);

    k_gemm<0><<<dim3(24, 16), 256, 0, stream>>>(xn, wqkvT, 2048, 3072, 2048,
                                                qkv, nullptr, nullptr, nullptr);

    k_tau<<<2048, 256, 0, stream>>>(qkv, twq, twv, alpha, pos, tauq, tauv);
    k_heads<<<512, 256, 0, stream>>>(qkv, cosb, sinb, tauq, tauv, Qr, Kr, Vt);

    k_attn<<<dim3(32, 16), 256, 0, stream>>>(Qr, Kr, Vt, aout);

    k_gemm<2><<<dim3(16, 16), 256, 0, stream>>>(aout, woT, 2048, 2048, 2048,
                                                out, nullptr, nullptr, hidden);
    k_gemm<1><<<dim3(64, 16), 256, 0, stream>>>(xn, upT, 2048, 8192, 2048,
                                                nullptr, hbuf, up_b, nullptr);
    k_gemm<3><<<dim3(16, 16), 256, 0, stream>>>(hbuf, downT, 2048, 2048, 8192,
                                                out, nullptr, down_b, nullptr);
}

// Round 4
// 604.726 us; speedup vs baseline: 1.1901x; 1.0106x over previous
//
#include <hip/hip_runtime.h>
#include <hip/hip_bf16.h>
#include <math.h>

typedef __bf16 bf16;
typedef bf16 bf16x4 __attribute__((ext_vector_type(4)));
typedef bf16 bf16x8 __attribute__((ext_vector_type(8)));
typedef float f32x4 __attribute__((ext_vector_type(4)));

// ---------------------------------------------------------------------------
// Transpose + f32->bf16 cast: src (R x C) f32 row-major -> dst (C x R) bf16.
// ---------------------------------------------------------------------------
__global__ __launch_bounds__(256) void k_transpose(const float* __restrict__ src,
                                                   bf16* __restrict__ dst,
                                                   int R, int C, int dstStride) {
    __shared__ float tile[32][33];
    int bc = blockIdx.x * 32, br = blockIdx.y * 32;
    int tx = threadIdx.x & 31, ty = threadIdx.x >> 5;
    for (int i = 0; i < 4; i++) {
        int r = ty + i * 8;
        tile[r][tx] = src[(size_t)(br + r) * C + bc + tx];
    }
    __syncthreads();
    for (int i = 0; i < 4; i++) {
        int r = ty + i * 8;
        dst[(size_t)(bc + r) * dstStride + br + tx] = (bf16)tile[tx][r];
    }
}

// ---------------------------------------------------------------------------
// LayerNorm: per-token mean/var over H=2048, write bf16 xn.
// ---------------------------------------------------------------------------
__global__ __launch_bounds__(256) void k_ln(const float* __restrict__ x,
                                            const float* __restrict__ w,
                                            const float* __restrict__ b,
                                            bf16* __restrict__ xn) {
    int s = blockIdx.x;
    int t = threadIdx.x;
    const float* row = x + (size_t)s * 2048;
    const float4* r4 = (const float4*)row;
    float4 A = r4[t * 2], B = r4[t * 2 + 1];
    float sum = A.x + A.y + A.z + A.w + B.x + B.y + B.z + B.w;
    float sq = A.x * A.x + A.y * A.y + A.z * A.z + A.w * A.w +
               B.x * B.x + B.y * B.y + B.z * B.z + B.w * B.w;
    for (int off = 32; off; off >>= 1) {
        sum += __shfl_down(sum, off);
        sq  += __shfl_down(sq, off);
    }
    __shared__ float rs[4], rq[4];
    if ((t & 63) == 0) { rs[t >> 6] = sum; rq[t >> 6] = sq; }
    __syncthreads();
    float S = rs[0] + rs[1] + rs[2] + rs[3];
    float Q = rq[0] + rq[1] + rq[2] + rq[3];
    float mu = S * (1.0f / 2048.0f);
    float var = Q * (1.0f / 2048.0f) - mu * mu;
    float rstd = rsqrtf(var + 1e-5f);
    float vals[8] = {A.x, A.y, A.z, A.w, B.x, B.y, B.z, B.w};
    bf16x8 ov;
    int j0 = t * 8;
    for (int i = 0; i < 8; i++)
        ov[i] = (bf16)((vals[i] - mu) * rstd * w[j0 + i] + b[j0 + i]);
    *(bf16x8*)&xn[(size_t)s * 2048 + j0] = ov;
}

// ---------------------------------------------------------------------------
// MFMA bf16 GEMM, m97 structure: C = A(MxK) @ Bt(NxK)^T.
// 128x128 tile, BK=64, linear LDS [128][64], global_load_lds width-16 staging,
// 2 barriers per K-step. Optional split-K via blockIdx.z (kslice elements per
// slice; Cf offset by z*M*N).
// MODE 0: Cf = acc (also used for split-K partials)
// MODE 1: Cb = gelu_tanh(acc + bias)  (bf16 out)
// ---------------------------------------------------------------------------
template <int MODE>
__global__ __launch_bounds__(256) void k_gemm(const bf16* __restrict__ A,
                                              const bf16* __restrict__ Bt,
                                              int M, int N, int K, int kslice,
                                              float* __restrict__ Cf,
                                              bf16* __restrict__ Cb,
                                              const float* __restrict__ bias) {
    __shared__ bf16 As[128][64];
    __shared__ bf16 Bs[128][64];
    int t = threadIdx.x;
    int bm = blockIdx.y, bn = blockIdx.x, bz = blockIdx.z;
    int w = t >> 6, l = t & 63, lr = l & 15, lg = l >> 4;
    int wm = w >> 1, wn = w & 1;
    f32x4 acc[4][4] = {};
    const bf16* Ab = A + (size_t)(bm * 128) * K + (size_t)bz * kslice;
    const bf16* Bb = Bt + (size_t)(bn * 128) * K + (size_t)bz * kslice;
    int srow = t >> 3;          // 0..31: staging row within 32-row chunk
    int scol = (t & 7) * 8;     // staging col (elements)
    int nkt = kslice >> 6;
    for (int kt = 0; kt < nkt; ++kt) {
        int k0 = kt * 64;
        if (kt) __syncthreads();  // prior compute done reading LDS
#pragma unroll
        for (int i = 0; i < 4; i++) {
            const bf16* ga = Ab + (size_t)(i * 32 + srow) * K + k0 + scol;
            const bf16* gb = Bb + (size_t)(i * 32 + srow) * K + k0 + scol;
            char* la = (char*)(&As[0][0]) + i * 4096 + w * 1024;
            char* lb = (char*)(&Bs[0][0]) + i * 4096 + w * 1024;
            __builtin_amdgcn_global_load_lds(
                (const __attribute__((address_space(1))) void*)ga,
                (__attribute__((address_space(3))) void*)la, 16, 0, 0);
            __builtin_amdgcn_global_load_lds(
                (const __attribute__((address_space(1))) void*)gb,
                (__attribute__((address_space(3))) void*)lb, 16, 0, 0);
        }
        asm volatile("s_waitcnt vmcnt(0)" ::: "memory");
        __syncthreads();
#pragma unroll
        for (int kk = 0; kk < 2; kk++) {
            bf16x8 a[4], b[4];
            for (int fm = 0; fm < 4; fm++)
                a[fm] = *(const bf16x8*)&As[wm * 64 + fm * 16 + lr][kk * 32 + lg * 8];
            for (int fn = 0; fn < 4; fn++)
                b[fn] = *(const bf16x8*)&Bs[wn * 64 + fn * 16 + lr][kk * 32 + lg * 8];
            for (int fm = 0; fm < 4; fm++)
                for (int fn = 0; fn < 4; fn++)
                    acc[fm][fn] = __builtin_amdgcn_mfma_f32_16x16x32_bf16(
                        a[fm], b[fn], acc[fm][fn], 0, 0, 0);
        }
    }
    float* Cz = Cf + (size_t)bz * M * N;
    for (int fm = 0; fm < 4; fm++)
        for (int fn = 0; fn < 4; fn++) {
            int col = bn * 128 + wn * 64 + fn * 16 + lr;
            for (int r = 0; r < 4; r++) {
                int row = bm * 128 + wm * 64 + fm * 16 + lg * 4 + r;
                size_t idx = (size_t)row * N + col;
                float v = acc[fm][fn][r];
                if constexpr (MODE == 0) {
                    Cz[idx] = v;
                } else {
                    v += bias[col];
                    float g = 0.5f * v * (1.0f + tanhf(0.7978845608028654f *
                                                       (v + 0.044715f * v * v * v)));
                    Cb[idx] = (bf16)g;
                }
            }
        }
}

// ---------------------------------------------------------------------------
// Final fuse: out = hidden + (W0+W1) + (P0+P1) + down_b.  float4 per thread.
// ---------------------------------------------------------------------------
__global__ __launch_bounds__(256) void k_final(const float* __restrict__ hidden,
                                               const float* __restrict__ w0,
                                               const float* __restrict__ w1,
                                               const float* __restrict__ p0,
                                               const float* __restrict__ p1,
                                               const float* __restrict__ bias,
                                               float* __restrict__ out) {
    int idx = blockIdx.x * 256 + threadIdx.x;  // float4 index
    int col4 = idx & 511;                      // 2048/4 float4 per row
    float4 b = ((const float4*)bias)[col4];
    float4 h = ((const float4*)hidden)[idx];
    float4 a0 = ((const float4*)w0)[idx];
    float4 a1 = ((const float4*)w1)[idx];
    float4 d0 = ((const float4*)p0)[idx];
    float4 d1 = ((const float4*)p1)[idx];
    float4 o;
    o.x = h.x + a0.x + a1.x + d0.x + d1.x + b.x;
    o.y = h.y + a0.y + a1.y + d0.y + d1.y + b.y;
    o.z = h.z + a0.z + a1.z + d0.z + d1.z + b.z;
    o.w = h.w + a0.w + a1.w + d0.w + d1.w + b.w;
    ((float4*)out)[idx] = o;
}

// ---------------------------------------------------------------------------
// tau weights per token (position_ids arrive as int32 from the harness).
// ---------------------------------------------------------------------------
__global__ __launch_bounds__(256) void k_tau(const float* __restrict__ qkv,
                                             const float* __restrict__ twq,
                                             const float* __restrict__ twv,
                                             const float* __restrict__ alpha,
                                             const int* __restrict__ pos,
                                             float* __restrict__ tauq,
                                             float* __restrict__ tauv) {
    int s = blockIdx.x;
    __shared__ float tok[3072];
    __shared__ float part[4][64];
    const float* row = qkv + (size_t)s * 3072;
    for (int j = threadIdx.x; j < 3072; j += 256) {
        float x = row[j];
        tok[j] = x * 0.5f * (1.0f + erff(x * 0.7071067811865475f));
    }
    __syncthreads();
    int h = threadIdx.x & 63;
    int chunk = threadIdx.x >> 6;
    const float* W = (h < 32) ? twq : twv;
    int hh = h & 31;
    float acc = 0.0f;
    int j0 = chunk * 768;
    for (int j = j0; j < j0 + 768; ++j) acc += tok[j] * W[j * 32 + hh];
    part[chunk][h] = acc;
    __syncthreads();
    if (chunk == 0) {
        float tot = part[0][h] + part[1][h] + part[2][h] + part[3][h];
        float pf = (float)(pos[s] + 1);
        float lp = logf(pf);
        float tp = 1.0f + (1.0f / (1.0f + expf(-alpha[hh] * lp)) - 0.5f);
        float val = tanhf(tot) + tp;
        if (h < 32) tauq[s * 32 + hh] = val;
        else        tauv[s * 32 + hh] = val;
    }
}

// ---------------------------------------------------------------------------
// Head build: RoPE + tau scaling; Vt stored (kvh*64+d, s).
// ---------------------------------------------------------------------------
__global__ __launch_bounds__(256) void k_heads(const float* __restrict__ qkv,
                                               const float* __restrict__ cosb,
                                               const float* __restrict__ sinb,
                                               const float* __restrict__ tauq,
                                               const float* __restrict__ tauv,
                                               bf16* __restrict__ Qr,
                                               bf16* __restrict__ Kr,
                                               bf16* __restrict__ Vt) {
    int s = blockIdx.x * 4 + (threadIdx.x >> 6);
    int d = threadIdx.x & 63;
    int j = (d >> 1) & 15;
    float c = cosb[s * 16 + j], sn = sinb[s * 16 + j];
    const float* row = qkv + (size_t)s * 3072;
    for (int h = 0; h < 32; ++h) {
        float x = row[h * 64 + d] * tauq[s * 32 + h] * 0.125f;
        float xr = __shfl(x, j);
        float xi = __shfl(x, j + 16);
        float out = (d < 32) ? ((d & 1) ? (xr * sn + xi * c) : (xr * c - xi * sn)) : x;
        Qr[(size_t)s * 2048 + h * 64 + d] = (bf16)out;
    }
    for (int h = 0; h < 8; ++h) {
        float x = row[2048 + h * 64 + d];
        float xr = __shfl(x, j);
        float xi = __shfl(x, j + 16);
        float out = (d < 32) ? ((d & 1) ? (xr * sn + xi * c) : (xr * c - xi * sn)) : x;
        Kr[(size_t)s * 512 + h * 64 + d] = (bf16)out;
    }
    for (int h = 0; h < 8; ++h) {
        float x = row[2560 + h * 64 + d] * tauv[s * 32 + h];
        Vt[((size_t)h * 64 + d) * 2048 + s] = (bf16)x;
    }
}

// ---------------------------------------------------------------------------
// Flash attention (causal, GQA 32/8, D=64), swapped-operand layout.
// ---------------------------------------------------------------------------
__global__ __launch_bounds__(256) void k_attn(const bf16* __restrict__ Q,
                                              const bf16* __restrict__ K,
                                              const bf16* __restrict__ Vt,
                                              bf16* __restrict__ O) {
    __shared__ bf16 plds[4][16][40];
    int w = threadIdx.x >> 6, l = threadIdx.x & 63, lr = l & 15, lg = l >> 4;
    int h = blockIdx.x, kvh = h >> 2;
    int slot = blockIdx.y * 4 + w;
    const bf16* Kb = K + (size_t)kvh * 64;
    const bf16* Vb = Vt + ((size_t)kvh * 64) * 2048;

    for (int pass = 0; pass < 2; ++pass) {
        int qt = pass ? (127 - slot) : slot;
        int qrow0 = qt * 16;
        int qg = qrow0 + lr;
        bf16x8 q0 = *(const bf16x8*)&Q[(size_t)qg * 2048 + h * 64 + lg * 8];
        bf16x8 q1 = *(const bf16x8*)&Q[(size_t)qg * 2048 + h * 64 + 32 + lg * 8];
        f32x4 o[4] = {};
        float m = -3e38f, ll = 0.0f;
        int nkt = (qrow0 + 15) / 32 + 1;
        bf16x8 kf[4];
        for (int kc = 0; kc < 2; kc++)
            for (int dd = 0; dd < 2; dd++)
                kf[kc * 2 + dd] = *(const bf16x8*)&Kb[(size_t)(kc * 16 + lr) * 512 + dd * 32 + lg * 8];
        for (int kt = 0; kt < nkt; ++kt) {
            int kb = kt * 32;
            bf16x8 vf[4];
            for (int fn = 0; fn < 4; fn++)
                vf[fn] = *(const bf16x8*)&Vb[(size_t)(fn * 16 + lr) * 2048 + kb + lg * 8];
            f32x4 sc[2];
            for (int kc = 0; kc < 2; kc++) {
                f32x4 z = {};
                z = __builtin_amdgcn_mfma_f32_16x16x32_bf16(kf[kc * 2], q0, z, 0, 0, 0);
                sc[kc] = __builtin_amdgcn_mfma_f32_16x16x32_bf16(kf[kc * 2 + 1], q1, z, 0, 0, 0);
            }
            int kbn = (kt + 1 < nkt) ? (kt + 1) * 32 : kt * 32;
            for (int kc = 0; kc < 2; kc++)
                for (int dd = 0; dd < 2; dd++)
                    kf[kc * 2 + dd] = *(const bf16x8*)&Kb[(size_t)(kbn + kc * 16 + lr) * 512 + dd * 32 + lg * 8];
            float tmax = -3e38f;
            for (int kc = 0; kc < 2; kc++)
                for (int r = 0; r < 4; r++) {
                    int kg = kb + kc * 16 + lg * 4 + r;
                    if (kg > qg) sc[kc][r] = -1e30f;
                    tmax = fmaxf(tmax, sc[kc][r]);
                }
            tmax = fmaxf(tmax, __shfl_xor(tmax, 16));
            tmax = fmaxf(tmax, __shfl_xor(tmax, 32));
            float mn = fmaxf(m, tmax);
            float al = __expf(m - mn);
            m = mn;
            float rsum = 0.0f;
            f32x4 p[2];
            for (int kc = 0; kc < 2; kc++)
                for (int r = 0; r < 4; r++) {
                    float pv = __expf(sc[kc][r] - mn);
                    p[kc][r] = pv;
                    rsum += pv;
                }
            rsum += __shfl_xor(rsum, 16);
            rsum += __shfl_xor(rsum, 32);
            ll = ll * al + rsum;
            for (int fn = 0; fn < 4; fn++)
                for (int r = 0; r < 4; r++) o[fn][r] *= al;
            for (int kc = 0; kc < 2; kc++) {
                bf16x4 pk;
                for (int r = 0; r < 4; r++) pk[r] = (bf16)p[kc][r];
                *(bf16x4*)&plds[w][lr][kc * 16 + lg * 4] = pk;
            }
            asm volatile("s_waitcnt lgkmcnt(0)" ::: "memory");
            bf16x8 pa = *(const bf16x8*)&plds[w][lr][lg * 8];
            for (int fn = 0; fn < 4; fn++)
                o[fn] = __builtin_amdgcn_mfma_f32_16x16x32_bf16(vf[fn], pa, o[fn], 0, 0, 0);
        }
        float rinv = 1.0f / ll;
        for (int fn = 0; fn < 4; fn++) {
            bf16x4 ov;
            for (int r = 0; r < 4; r++) ov[r] = (bf16)(o[fn][r] * rinv);
            *(bf16x4*)&O[(size_t)qg * 2048 + h * 64 + fn * 16 + lg * 4] = ov;
        }
    }
}

// ---------------------------------------------------------------------------
extern "C" void kernel_launch(void* const* d_in, const int* in_sizes, int n_in,
                              void* d_out, int out_size, void* d_ws, size_t ws_size,
                              hipStream_t stream) {
    const float* hidden = (const float*)d_in[0];
    const int*   pos    = (const int*)d_in[1];   // harness converts int64 -> int32
    const float* cosb   = (const float*)d_in[2];
    const float* sinb   = (const float*)d_in[3];
    const float* ln_w   = (const float*)d_in[4];
    const float* ln_b   = (const float*)d_in[5];
    const float* wq     = (const float*)d_in[6];
    const float* wk     = (const float*)d_in[7];
    const float* wv     = (const float*)d_in[8];
    const float* wo     = (const float*)d_in[9];
    const float* twq    = (const float*)d_in[10];
    const float* twv    = (const float*)d_in[11];
    const float* alpha  = (const float*)d_in[12];
    const float* up_w   = (const float*)d_in[13];
    const float* up_b   = (const float*)d_in[14];
    const float* down_w = (const float*)d_in[15];
    const float* down_b = (const float*)d_in[16];
    float* out = (float*)d_out;

    char* p = (char*)d_ws;
    auto alloc = [&](size_t n) -> char* {
        char* r = p;
        p += (n + 255) & ~(size_t)255;
        return r;
    };
    bf16* wqkvT = (bf16*)alloc((size_t)3072 * 2048 * 2);
    bf16* woT   = (bf16*)alloc((size_t)2048 * 2048 * 2);
    bf16* upT   = (bf16*)alloc((size_t)8192 * 2048 * 2);
    bf16* downT = (bf16*)alloc((size_t)2048 * 8192 * 2);
    bf16* xn    = (bf16*)alloc((size_t)2048 * 2048 * 2);
    float* qkv  = (float*)alloc((size_t)2048 * 3072 * 4);
    float* tauq = (float*)alloc((size_t)2048 * 32 * 4);
    float* tauv = (float*)alloc((size_t)2048 * 32 * 4);
    bf16* Qr    = (bf16*)alloc((size_t)2048 * 2048 * 2);
    bf16* Kr    = (bf16*)alloc((size_t)2048 * 512 * 2);
    bf16* Vt    = (bf16*)alloc((size_t)8 * 64 * 2048 * 2);
    bf16* aout  = (bf16*)alloc((size_t)2048 * 2048 * 2);
    bf16* hbuf  = (bf16*)alloc((size_t)2048 * 8192 * 2);
    float* Wp   = (float*)alloc((size_t)2 * 2048 * 2048 * 4);  // wo split-K partials
    float* Pp   = (float*)alloc((size_t)2 * 2048 * 2048 * 4);  // down split-K partials

    k_transpose<<<dim3(64, 64), 256, 0, stream>>>(wq, wqkvT, 2048, 2048, 2048);
    k_transpose<<<dim3(16, 64), 256, 0, stream>>>(wk, wqkvT + (size_t)2048 * 2048, 2048, 512, 2048);
    k_transpose<<<dim3(16, 64), 256, 0, stream>>>(wv, wqkvT + (size_t)2560 * 2048, 2048, 512, 2048);
    k_transpose<<<dim3(64, 64), 256, 0, stream>>>(wo, woT, 2048, 2048, 2048);
    k_transpose<<<dim3(256, 64), 256, 0, stream>>>(up_w, upT, 2048, 8192, 2048);
    k_transpose<<<dim3(64, 256), 256, 0, stream>>>(down_w, downT, 8192, 2048, 8192);

    k_ln<<<2048, 256, 0, stream>>>(hidden, ln_w, ln_b, xn);

    // qkv = xn @ [wq|wk|wv]   (384 blocks)
    k_gemm<0><<<dim3(24, 16, 1), 256, 0, stream>>>(xn, wqkvT, 2048, 3072, 2048, 2048,
                                                   qkv, nullptr, nullptr);

    k_tau<<<2048, 256, 0, stream>>>(qkv, twq, twv, alpha, pos, tauq, tauv);
    k_heads<<<512, 256, 0, stream>>>(qkv, cosb, sinb, tauq, tauv, Qr, Kr, Vt);

    k_attn<<<dim3(32, 16), 256, 0, stream>>>(Qr, Kr, Vt, aout);

    // wo partials: aout @ woT, split-K 2 (512 blocks)
    k_gemm<0><<<dim3(16, 16, 2), 256, 0, stream>>>(aout, woT, 2048, 2048, 2048, 1024,
                                                   Wp, nullptr, nullptr);
    // h = gelu_tanh(xn @ up_w + up_b)   (1024 blocks)
    k_gemm<1><<<dim3(64, 16, 1), 256, 0, stream>>>(xn, upT, 2048, 8192, 2048, 2048,
                                                   nullptr, hbuf, up_b);
    // down partials: hbuf @ downT, split-K 2 (512 blocks)
    k_gemm<0><<<dim3(16, 16, 2), 256, 0, stream>>>(hbuf, downT, 2048, 2048, 8192, 4096,
                                                   Pp, nullptr, nullptr);
    // out = hidden + W0+W1 + P0+P1 + down_b
    k_final<<<4096, 256, 0, stream>>>(hidden, Wp, Wp + (size_t)2048 * 2048,
                                      Pp, Pp + (size_t)2048 * 2048, down_b, out);
}